// Round 1
// baseline (564.257 us; speedup 1.0000x reference)
//
#include <hip/hip_runtime.h>

// ---------------------------------------------------------------------------
// SwitchMLP (top-1 MoE, SwiGLU experts) for MI355X / gfx950.
// S=1024 B=4 DIM=768 HID=2048 E=8, all inputs f32, output f32.
//
// Pipeline: init(zero counts) -> router(f64 logits, argmax, gather lists,
// x->f16) -> gemm1(x@w1, x@w2 fused, silu-mul, ->f16 H) -> gemm2(H@w3,
// bf16-RNE cast, *prob, scatter f32 out).
// ---------------------------------------------------------------------------

#define T_TOK 4096
#define DIM   768
#define HID   2048
#define NE    8

typedef _Float16 f16x8 __attribute__((ext_vector_type(8)));
typedef float    f32x4 __attribute__((ext_vector_type(4)));

// LDS tile rows: 32 f16 of data + 8 f16 pad = 40 f16 (80 B) to break
// power-of-2 bank strides on the transposed-B scalar writes.
#define LDS_ROW 40

__device__ __forceinline__ float bf16_rne(float v) {
    // round-to-nearest-even f32 -> bf16 -> f32 (values are finite here)
    unsigned u = __float_as_uint(v);
    unsigned r = (u + 0x7fffu + ((u >> 16) & 1u)) & 0xffff0000u;
    return __uint_as_float(r);
}

// ---------------------------------------------------------------------------
__global__ void moe_init_kernel(int* __restrict__ counts) {
    if (threadIdx.x < NE) counts[threadIdx.x] = 0;
}

// ---------------------------------------------------------------------------
// One wave per token: f64 logits (argmax robustness), softmax max-prob,
// atomic append to the owning expert's token list, write f16 copy of x.
__global__ __launch_bounds__(256) void moe_router_kernel(
    const float* __restrict__ X, const float* __restrict__ rw,
    const float* __restrict__ rb, float* __restrict__ probs,
    int* __restrict__ counts, int* __restrict__ lists,
    _Float16* __restrict__ Xg)
{
    const int t    = blockIdx.x * 4 + (threadIdx.x >> 6);
    const int lane = threadIdx.x & 63;
    const float* x = X + (size_t)t * DIM;

    float xv[12];
#pragma unroll
    for (int j = 0; j < 12; ++j) xv[j] = x[lane + j * 64];
#pragma unroll
    for (int j = 0; j < 12; ++j)
        Xg[(size_t)t * DIM + lane + j * 64] = (_Float16)xv[j];

    double lg[NE];
#pragma unroll
    for (int e = 0; e < NE; ++e) {
        double s = 0.0;
#pragma unroll
        for (int j = 0; j < 12; ++j)
            s += (double)xv[j] * (double)rw[(lane + j * 64) * NE + e];
#pragma unroll
        for (int off = 32; off >= 1; off >>= 1) s += __shfl_xor(s, off, 64);
        lg[e] = s + (double)rb[e];
    }

    if (lane == 0) {
        double m = lg[0]; int mi = 0;
#pragma unroll
        for (int e = 1; e < NE; ++e)
            if (lg[e] > m) { m = lg[e]; mi = e; }   // strict > keeps first max
        float sum = 0.f;
#pragma unroll
        for (int e = 0; e < NE; ++e) sum += expf((float)(lg[e] - m));
        probs[t] = 1.0f / sum;                       // = max of softmax
        int pos = atomicAdd(&counts[mi], 1);
        lists[mi * T_TOK + pos] = t;
    }
}

// ---------------------------------------------------------------------------
// GEMM1: per expert e, A = gathered x rows (f16), B1 = w1[e], B2 = w2[e]
// (f32 -> f16 on stage). Tile 128x128, BK=32, 4 waves each 64x64.
// Epilogue: H[tok][n] = f16( silu(h1) * h2 ).
__global__ __launch_bounds__(256) void moe_gemm1_kernel(
    const _Float16* __restrict__ Xg, const int* __restrict__ lists,
    const int* __restrict__ counts, const float* __restrict__ w1,
    const float* __restrict__ w2, _Float16* __restrict__ H)
{
    const int e   = blockIdx.z;
    const int cnt = counts[e];
    const int m0  = blockIdx.y * 128;
    if (m0 >= cnt) return;
    const int n0  = blockIdx.x * 128;
    const int* list = lists + e * T_TOK;

    __shared__ __align__(16) _Float16 As [128 * LDS_ROW];
    __shared__ __align__(16) _Float16 B1s[128 * LDS_ROW];
    __shared__ __align__(16) _Float16 B2s[128 * LDS_ROW];

    const int tid  = threadIdx.x;
    const int lane = tid & 63;
    const int wave = tid >> 6;
    const int wr   = wave >> 1;      // wave row (0..1) -> 64 rows
    const int wc   = wave & 1;       // wave col (0..1) -> 64 cols
    const int frow = lane & 15;
    const int fq   = lane >> 4;      // quad 0..3

    // A staging: thread -> (row am, 16-f16 half ah)
    const int am = tid >> 1;
    const int ah = tid & 1;
    const int gm_a = m0 + am;
    const _Float16* aptr = nullptr;
    if (gm_a < cnt) aptr = Xg + (size_t)list[gm_a] * DIM + ah * 16;

    // B staging: thread -> (k-row bk, 16-col group bn)
    const int bk = tid >> 3;             // 0..31
    const int bn = (tid & 7) * 16;       // 0..112
    const float* b1base = w1 + ((size_t)e * DIM + bk) * HID + n0 + bn;
    const float* b2base = w2 + ((size_t)e * DIM + bk) * HID + n0 + bn;

    f32x4 acc1[4][4], acc2[4][4];
    const f32x4 zero = {0.f, 0.f, 0.f, 0.f};
#pragma unroll
    for (int i = 0; i < 4; ++i)
#pragma unroll
        for (int j = 0; j < 4; ++j) { acc1[i][j] = zero; acc2[i][j] = zero; }

    for (int k0 = 0; k0 < DIM; k0 += 32) {
        // ---- global loads (overlap with previous iter's MFMA) ----
        float4 av0, av1;
        if (aptr) {
            const float4* p = (const float4*)(aptr + k0);
            av0 = p[0]; av1 = p[1];
        } else {
            av0 = make_float4(0.f, 0.f, 0.f, 0.f); av1 = av0;
        }
        float4 b1v[4], b2v[4];
        const float* p1 = b1base + (size_t)k0 * HID;
        const float* p2 = b2base + (size_t)k0 * HID;
#pragma unroll
        for (int q = 0; q < 4; ++q) {
            b1v[q] = *(const float4*)(p1 + q * 4);
            b2v[q] = *(const float4*)(p2 + q * 4);
        }

        __syncthreads();   // prev iter's fragment reads done

        // ---- LDS writes ----
        *(float4*)(&As[am * LDS_ROW + ah * 16])     = av0;   // 8 f16
        *(float4*)(&As[am * LDS_ROW + ah * 16 + 8]) = av1;
#pragma unroll
        for (int q = 0; q < 4; ++q) {
            const int nb = bn + q * 4;
            B1s[(nb + 0) * LDS_ROW + bk] = (_Float16)b1v[q].x;
            B1s[(nb + 1) * LDS_ROW + bk] = (_Float16)b1v[q].y;
            B1s[(nb + 2) * LDS_ROW + bk] = (_Float16)b1v[q].z;
            B1s[(nb + 3) * LDS_ROW + bk] = (_Float16)b1v[q].w;
            B2s[(nb + 0) * LDS_ROW + bk] = (_Float16)b2v[q].x;
            B2s[(nb + 1) * LDS_ROW + bk] = (_Float16)b2v[q].y;
            B2s[(nb + 2) * LDS_ROW + bk] = (_Float16)b2v[q].z;
            B2s[(nb + 3) * LDS_ROW + bk] = (_Float16)b2v[q].w;
        }

        __syncthreads();

        // ---- fragments + MFMA ----
        f16x8 af[4], b1f[4], b2f[4];
#pragma unroll
        for (int i = 0; i < 4; ++i) {
            af[i]  = *(const f16x8*)(&As [(wr * 64 + i * 16 + frow) * LDS_ROW + fq * 8]);
            b1f[i] = *(const f16x8*)(&B1s[(wc * 64 + i * 16 + frow) * LDS_ROW + fq * 8]);
            b2f[i] = *(const f16x8*)(&B2s[(wc * 64 + i * 16 + frow) * LDS_ROW + fq * 8]);
        }
#pragma unroll
        for (int i = 0; i < 4; ++i)
#pragma unroll
            for (int j = 0; j < 4; ++j) {
                acc1[i][j] = __builtin_amdgcn_mfma_f32_16x16x32_f16(af[i], b1f[j], acc1[i][j], 0, 0, 0);
                acc2[i][j] = __builtin_amdgcn_mfma_f32_16x16x32_f16(af[i], b2f[j], acc2[i][j], 0, 0, 0);
            }
    }

    // ---- epilogue: silu(h1)*h2 -> f16 H, scattered by token ----
#pragma unroll
    for (int i = 0; i < 4; ++i) {
#pragma unroll
        for (int r = 0; r < 4; ++r) {
            const int gm = m0 + wr * 64 + i * 16 + fq * 4 + r;
            if (gm < cnt) {
                const int tok = list[gm];
                _Float16* hrow = H + (size_t)tok * HID + n0 + wc * 64 + frow;
#pragma unroll
                for (int j = 0; j < 4; ++j) {
                    const float h1 = acc1[i][j][r];
                    const float h2 = acc2[i][j][r];
                    const float s  = h1 / (1.0f + __expf(-h1));  // silu
                    hrow[j * 16] = (_Float16)(s * h2);
                }
            }
        }
    }
}

// ---------------------------------------------------------------------------
// GEMM2: per expert, A = gathered H rows (f16), B = w3[e] (f32->f16 stage).
// Tile 64x128, BK=32, 4 waves each 64x32.
// Epilogue: out[tok][n] = bf16_rne(acc) * prob[tok]   (f32 store).
__global__ __launch_bounds__(256) void moe_gemm2_kernel(
    const _Float16* __restrict__ H, const int* __restrict__ lists,
    const int* __restrict__ counts, const float* __restrict__ w3,
    const float* __restrict__ probs, float* __restrict__ out)
{
    const int e   = blockIdx.z;
    const int cnt = counts[e];
    const int m0  = blockIdx.y * 64;
    if (m0 >= cnt) return;
    const int n0  = blockIdx.x * 128;
    const int* list = lists + e * T_TOK;

    __shared__ __align__(16) _Float16 As[64 * LDS_ROW];
    __shared__ __align__(16) _Float16 Bs[128 * LDS_ROW];

    const int tid  = threadIdx.x;
    const int lane = tid & 63;
    const int wave = tid >> 6;       // wave -> 32-col slice
    const int frow = lane & 15;
    const int fq   = lane >> 4;

    // A staging: thread -> (row am 0..63, 8-f16 chunk ch 0..3)
    const int am = tid >> 2;
    const int ch = tid & 3;
    const int gm_a = m0 + am;
    const _Float16* aptr = nullptr;
    if (gm_a < cnt) aptr = H + (size_t)list[gm_a] * HID + ch * 8;

    // B staging: thread -> (k-row bk 0..31, 16-col group bn)
    const int bk = tid >> 3;
    const int bn = (tid & 7) * 16;
    const float* bbase = w3 + ((size_t)e * HID + bk) * DIM + n0 + bn;

    f32x4 acc[4][2];
    const f32x4 zero = {0.f, 0.f, 0.f, 0.f};
#pragma unroll
    for (int i = 0; i < 4; ++i) { acc[i][0] = zero; acc[i][1] = zero; }

    for (int k0 = 0; k0 < HID; k0 += 32) {
        float4 av;
        if (aptr) av = *(const float4*)(aptr + k0);
        else      av = make_float4(0.f, 0.f, 0.f, 0.f);
        float4 bv[4];
        const float* p = bbase + (size_t)k0 * DIM;
#pragma unroll
        for (int q = 0; q < 4; ++q) bv[q] = *(const float4*)(p + q * 4);

        __syncthreads();

        *(float4*)(&As[am * LDS_ROW + ch * 8]) = av;
#pragma unroll
        for (int q = 0; q < 4; ++q) {
            const int nb = bn + q * 4;
            Bs[(nb + 0) * LDS_ROW + bk] = (_Float16)bv[q].x;
            Bs[(nb + 1) * LDS_ROW + bk] = (_Float16)bv[q].y;
            Bs[(nb + 2) * LDS_ROW + bk] = (_Float16)bv[q].z;
            Bs[(nb + 3) * LDS_ROW + bk] = (_Float16)bv[q].w;
        }

        __syncthreads();

        f16x8 af[4], bf[2];
#pragma unroll
        for (int i = 0; i < 4; ++i)
            af[i] = *(const f16x8*)(&As[(i * 16 + frow) * LDS_ROW + fq * 8]);
#pragma unroll
        for (int j = 0; j < 2; ++j)
            bf[j] = *(const f16x8*)(&Bs[(wave * 32 + j * 16 + frow) * LDS_ROW + fq * 8]);
#pragma unroll
        for (int i = 0; i < 4; ++i)
#pragma unroll
            for (int j = 0; j < 2; ++j)
                acc[i][j] = __builtin_amdgcn_mfma_f32_16x16x32_f16(af[i], bf[j], acc[i][j], 0, 0, 0);
    }

#pragma unroll
    for (int i = 0; i < 4; ++i) {
#pragma unroll
        for (int r = 0; r < 4; ++r) {
            const int gm = m0 + i * 16 + fq * 4 + r;
            if (gm < cnt) {
                const int tok = list[gm];
                const float pb = probs[tok];
                float* orow = out + (size_t)tok * DIM + n0 + wave * 32 + frow;
#pragma unroll
                for (int j = 0; j < 2; ++j)
                    orow[j * 16] = bf16_rne(acc[i][j][r]) * pb;
            }
        }
    }
}

// ---------------------------------------------------------------------------
extern "C" void kernel_launch(void* const* d_in, const int* in_sizes, int n_in,
                              void* d_out, int out_size, void* d_ws, size_t ws_size,
                              hipStream_t stream) {
    const float* X  = (const float*)d_in[0];   // [1024,4,768] -> [4096][768]
    const float* rw = (const float*)d_in[1];   // [768,8]
    const float* rb = (const float*)d_in[2];   // [8]
    const float* w1 = (const float*)d_in[3];   // [8,768,2048]
    const float* w2 = (const float*)d_in[4];   // [8,768,2048]
    const float* w3 = (const float*)d_in[5];   // [8,2048,768]
    float* out = (float*)d_out;                // [4096,768] f32

    // workspace layout (bytes)
    char* ws = (char*)d_ws;
    int*       counts = (int*)(ws + 0);            //     32 B (pad to 256)
    int*       lists  = (int*)(ws + 256);          // 131072 B
    float*     probs  = (float*)(ws + 131328);     //  16384 B
    _Float16*  Xg     = (_Float16*)(ws + 147712);  // 4096*768*2  = 6 MB
    _Float16*  H      = (_Float16*)(ws + 6439168); // 4096*2048*2 = 16 MB
    // total ~22.1 MB

    hipLaunchKernelGGL(moe_init_kernel, dim3(1), dim3(64), 0, stream, counts);
    hipLaunchKernelGGL(moe_router_kernel, dim3(T_TOK / 4), dim3(256), 0, stream,
                       X, rw, rb, probs, counts, lists, Xg);
    hipLaunchKernelGGL(moe_gemm1_kernel, dim3(HID / 128, T_TOK / 128, NE),
                       dim3(256), 0, stream, Xg, lists, counts, w1, w2, H);
    hipLaunchKernelGGL(moe_gemm2_kernel, dim3(DIM / 128, T_TOK / 64, NE),
                       dim3(256), 0, stream, H, lists, counts, w3, probs, out);
}

// Round 2
// 349.226 us; speedup vs baseline: 1.6157x; 1.6157x over previous
//
#include <hip/hip_runtime.h>

// ---------------------------------------------------------------------------
// SwitchMLP (top-1 MoE, SwiGLU) for MI355X / gfx950.  S=1024 B=4 DIM=768
// HID=2048 E=8, f32 in/out.
//
// Design: all GEMM operands are pre-staged in f16 *in MFMA fragment order*,
// so the GEMM K-loops are pure global_load_dwordx4 -> v_mfma with no LDS,
// no barriers, no conversion (fine-grained vmcnt pipelining by compiler).
//   convert: w1/w2/w3 f32 [K][N] -> swizzled f16 B-operand cells
//   router : f64 logits, argmax, per-expert token lists, max-prob
//   gather : X rows -> Ag (A-operand cells, zero-padded to 64-row tiles)
//   gemm1  : h = silu(A@W1)*(A@W2), epilogue LDS-transposes C->A layout -> Hs
//   gemm2  : out[tok] = bf16_rne(Hs@W3) * prob[tok]
//
// Fragment layouts (HW-validated by round-1 passing kernel):
//   A-op: lane l holds A[m=l&15][k=(l>>4)*8+j]   (cell = 16m x 32k = 512 f16)
//   B-op: lane l holds B[k=(l>>4)*8+j][n=l&15]   (cell = 32k x 16n = 512 f16)
//   C/D : lane l holds C[row=(l>>4)*4+r][col=l&15]
// ---------------------------------------------------------------------------

#define T_TOK 4096
#define DIM   768
#define HID   2048
#define NE    8
#define ECAP  1024           // per-expert token capacity (~24 sigma margin)

#define KB1 (DIM / 32)       // 24  k-cells, gemm1
#define NB1 (HID / 16)       // 128 n-cells, w1/w2
#define KB2 (HID / 32)       // 64  k-cells, gemm2
#define NB2 (DIM / 16)       // 48  n-cells, w3
#define MBC (ECAP / 16)      // 64  m-cells per expert

typedef _Float16 f16x8 __attribute__((ext_vector_type(8)));
typedef _Float16 f16x4 __attribute__((ext_vector_type(4)));
typedef float    f32x4 __attribute__((ext_vector_type(4)));

__device__ __forceinline__ float bf16_rne(float v) {
    unsigned u = __float_as_uint(v);
    unsigned r = (u + 0x7fffu + ((u >> 16) & 1u)) & 0xffff0000u;
    return __uint_as_float(r);
}

// ---------------------------------------------------------------------------
__global__ void moe_init_kernel(int* __restrict__ counts) {
    if (threadIdx.x < NE) counts[threadIdx.x] = 0;
}

// ---------------------------------------------------------------------------
// Convert+swizzle one 32k x 128n tile of one weight matrix into 8 B-operand
// cell columns. z encodes (matrix, expert). LDS transpose: read [k][n]
// coalesced (4 float4 rows of 4 cols), write LDS [n][k] as f16x4 (2-way bank
// aliasing only), read back f16x8 per lane in fragment order.
__global__ __launch_bounds__(256) void moe_convert_kernel(
    const float* __restrict__ w1, const float* __restrict__ w2,
    const float* __restrict__ w3, _Float16* __restrict__ w1s,
    _Float16* __restrict__ w2s, _Float16* __restrict__ w3s)
{
    const int z = blockIdx.z, e = z & 7, mat = z >> 3;
    const float* src; _Float16* dst; int K, N;
    if (mat == 0)      { src = w1 + (size_t)e * DIM * HID; dst = w1s + (size_t)e * NB1 * KB1 * 512; K = DIM; N = HID; }
    else if (mat == 1) { src = w2 + (size_t)e * DIM * HID; dst = w2s + (size_t)e * NB1 * KB1 * 512; K = DIM; N = HID; }
    else               { src = w3 + (size_t)e * HID * DIM; dst = w3s + (size_t)e * NB2 * KB2 * 512; K = HID; N = DIM; }
    const int ngrp = blockIdx.x, kb = blockIdx.y;
    if (ngrp * 128 >= N || kb * 32 >= K) return;
    const int KBc = K >> 5;

    __shared__ _Float16 Lt[128 * 40];   // [n][k], row 40 f16 = 80 B (16B-mult)
    const int t  = threadIdx.x;
    const int n4 = (t & 31) * 4;
    const int k4 = (t >> 5) * 4;
    const float* p = src + (size_t)(kb * 32 + k4) * N + ngrp * 128 + n4;
    float4 v[4];
#pragma unroll
    for (int j = 0; j < 4; ++j) v[j] = *(const float4*)(p + (size_t)j * N);
#pragma unroll
    for (int i = 0; i < 4; ++i) {
        f16x4 q;
#pragma unroll
        for (int j = 0; j < 4; ++j) q[j] = (_Float16)(((const float*)&v[j])[i]);
        *(f16x4*)&Lt[(n4 + i) * 40 + k4] = q;
    }
    __syncthreads();
    const int w = t >> 6, l = t & 63;
#pragma unroll
    for (int c = 0; c < 2; ++c) {
        const int nbl = w * 2 + c;
        f16x8 fr = *(const f16x8*)&Lt[(nbl * 16 + (l & 15)) * 40 + (l >> 4) * 8];
        const int nb = ngrp * 8 + nbl;
        *(f16x8*)(dst + ((size_t)nb * KBc + kb) * 512 + l * 8) = fr;
    }
}

// ---------------------------------------------------------------------------
// One wave per token: f64 logits (argmax robustness), max softmax prob,
// atomic append to owning expert's list.
__global__ __launch_bounds__(256) void moe_router_kernel(
    const float* __restrict__ X, const float* __restrict__ rw,
    const float* __restrict__ rb, float* __restrict__ probs,
    int* __restrict__ counts, int* __restrict__ lists)
{
    const int t    = blockIdx.x * 4 + (threadIdx.x >> 6);
    const int lane = threadIdx.x & 63;
    const float* x = X + (size_t)t * DIM;

    float xv[12];
#pragma unroll
    for (int j = 0; j < 12; ++j) xv[j] = x[lane + j * 64];

    double lg[NE];
#pragma unroll
    for (int e = 0; e < NE; ++e) {
        double s = 0.0;
#pragma unroll
        for (int j = 0; j < 12; ++j)
            s += (double)xv[j] * (double)rw[(lane + j * 64) * NE + e];
#pragma unroll
        for (int off = 32; off >= 1; off >>= 1) s += __shfl_xor(s, off, 64);
        lg[e] = s + (double)rb[e];
    }

    if (lane == 0) {
        double m = lg[0]; int mi = 0;
#pragma unroll
        for (int e = 1; e < NE; ++e)
            if (lg[e] > m) { m = lg[e]; mi = e; }
        float sum = 0.f;
#pragma unroll
        for (int e = 0; e < NE; ++e) sum += expf((float)(lg[e] - m));
        probs[t] = 1.0f / sum;
        int pos = atomicAdd(&counts[mi], 1);
        lists[mi * T_TOK + pos] = t;
    }
}

// ---------------------------------------------------------------------------
// Gather X rows per expert into A-operand cells (f16), zero-padding rows
// beyond cnt up to the 64-row tile boundary.
__global__ __launch_bounds__(256) void moe_gather_kernel(
    const float* __restrict__ X, const int* __restrict__ lists,
    const int* __restrict__ counts, _Float16* __restrict__ Ag)
{
    const int e = blockIdx.z;
    int cnt = counts[e]; if (cnt > ECAP) cnt = ECAP;
    const int mgrp = blockIdx.y;
    if (mgrp * 64 >= ((cnt + 63) & ~63)) return;
    const int t = threadIdx.x, w = t >> 6, l = t & 63;
    const int mb = mgrp * 4 + w;
    const int m  = mb * 16 + (l & 15);
    const bool valid = (m < cnt);
    const int tok = valid ? lists[e * T_TOK + m] : 0;
    const float* xr = X + (size_t)tok * DIM + (l >> 4) * 8;
#pragma unroll
    for (int i = 0; i < 4; ++i) {
        const int kb = blockIdx.x * 4 + i;
        float4 a = make_float4(0.f, 0.f, 0.f, 0.f), b = a;
        if (valid) {
            a = *(const float4*)(xr + kb * 32);
            b = *(const float4*)(xr + kb * 32 + 4);
        }
        f16x8 h;
        h[0] = (_Float16)a.x; h[1] = (_Float16)a.y; h[2] = (_Float16)a.z; h[3] = (_Float16)a.w;
        h[4] = (_Float16)b.x; h[5] = (_Float16)b.y; h[6] = (_Float16)b.z; h[7] = (_Float16)b.w;
        *(f16x8*)(Ag + ((size_t)(e * MBC + mb) * KB1 + kb) * 512 + l * 8) = h;
    }
}

// ---------------------------------------------------------------------------
// GEMM1: 64m x 128n block (wave = 64m x 32n, both W1 and W2). No LDS/barriers
// in the K-loop: direct fragment loads from Ag/w1s/w2s. Epilogue transposes
// C-layout -> A-layout through per-wave LDS and writes Hs cells.
__global__ __launch_bounds__(256) void moe_gemm1_kernel(
    const _Float16* __restrict__ Ag, const _Float16* __restrict__ w1s,
    const _Float16* __restrict__ w2s, const int* __restrict__ counts,
    _Float16* __restrict__ Hs)
{
    const int e = blockIdx.z;
    int cnt = counts[e]; if (cnt > ECAP) cnt = ECAP;
    const int by = blockIdx.y, bx = blockIdx.x;
    if (by * 64 >= cnt) return;
    const int t = threadIdx.x, w = t >> 6, l = t & 63;

    const _Float16* Ab  = Ag  + ((size_t)(e * MBC + by * 4) * KB1) * 512 + l * 8;
    const int nb0 = bx * 8 + w * 2;
    const _Float16* B1b = w1s + ((size_t)(e * NB1 + nb0) * KB1) * 512 + l * 8;
    const _Float16* B2b = w2s + ((size_t)(e * NB1 + nb0) * KB1) * 512 + l * 8;

    f32x4 acc1[4][2], acc2[4][2];
    const f32x4 zero = {0.f, 0.f, 0.f, 0.f};
#pragma unroll
    for (int i = 0; i < 4; ++i)
#pragma unroll
        for (int j = 0; j < 2; ++j) { acc1[i][j] = zero; acc2[i][j] = zero; }

#pragma unroll 2
    for (int kb = 0; kb < KB1; ++kb) {
        f16x8 a[4], b1[2], b2[2];
#pragma unroll
        for (int i = 0; i < 4; ++i)
            a[i] = *(const f16x8*)(Ab + (i * KB1 + kb) * 512);
#pragma unroll
        for (int j = 0; j < 2; ++j) {
            b1[j] = *(const f16x8*)(B1b + (j * KB1 + kb) * 512);
            b2[j] = *(const f16x8*)(B2b + (j * KB1 + kb) * 512);
        }
#pragma unroll
        for (int i = 0; i < 4; ++i)
#pragma unroll
            for (int j = 0; j < 2; ++j) {
                acc1[i][j] = __builtin_amdgcn_mfma_f32_16x16x32_f16(a[i], b1[j], acc1[i][j], 0, 0, 0);
                acc2[i][j] = __builtin_amdgcn_mfma_f32_16x16x32_f16(a[i], b2[j], acc2[i][j], 0, 0, 0);
            }
    }

    // epilogue: silu(h1)*h2 -> f16; C-layout -> A-layout via per-wave LDS
    __shared__ _Float16 Ep[4][64 * 40];
    const int fq = l >> 4, fr = l & 15;
#pragma unroll
    for (int i = 0; i < 4; ++i)
#pragma unroll
        for (int j = 0; j < 2; ++j)
#pragma unroll
            for (int r = 0; r < 4; ++r) {
                const float h1 = acc1[i][j][r], h2 = acc2[i][j][r];
                const float s  = h1 / (1.f + __expf(-h1)) * h2;
                Ep[w][(i * 16 + fq * 4 + r) * 40 + j * 16 + fr] = (_Float16)s;
            }
    __syncthreads();
    const int kbH = bx * 4 + w;          // this wave's 32-wide hid slice
#pragma unroll
    for (int i = 0; i < 4; ++i) {
        f16x8 v = *(const f16x8*)&Ep[w][(i * 16 + fr) * 40 + fq * 8];
        *(f16x8*)(Hs + ((size_t)(e * MBC + by * 4 + i) * KB2 + kbH) * 512 + l * 8) = v;
    }
}

// ---------------------------------------------------------------------------
// GEMM2: 32m x 128n block (wave = 32m x 32n), K=2048. Pure fragment-load
// K-loop, no LDS. Epilogue: bf16_rne(acc) * prob, scatter f32 by token.
__global__ __launch_bounds__(256) void moe_gemm2_kernel(
    const _Float16* __restrict__ Hs, const _Float16* __restrict__ w3s,
    const int* __restrict__ lists, const int* __restrict__ counts,
    const float* __restrict__ probs, float* __restrict__ out)
{
    const int e = blockIdx.z;
    int cnt = counts[e]; if (cnt > ECAP) cnt = ECAP;
    const int by = blockIdx.y, bx = blockIdx.x;
    const int m0 = by * 32;
    if (m0 >= cnt) return;
    const int t = threadIdx.x, w = t >> 6, l = t & 63;

    const _Float16* Ab = Hs  + ((size_t)(e * MBC + by * 2) * KB2) * 512 + l * 8;
    const int nb0 = bx * 8 + w * 2;
    const _Float16* Bb = w3s + ((size_t)(e * NB2 + nb0) * KB2) * 512 + l * 8;

    f32x4 acc[2][2];
    const f32x4 zero = {0.f, 0.f, 0.f, 0.f};
    acc[0][0] = zero; acc[0][1] = zero; acc[1][0] = zero; acc[1][1] = zero;

#pragma unroll 4
    for (int kb = 0; kb < KB2; ++kb) {
        f16x8 a[2], b[2];
#pragma unroll
        for (int i = 0; i < 2; ++i)
            a[i] = *(const f16x8*)(Ab + (i * KB2 + kb) * 512);
#pragma unroll
        for (int j = 0; j < 2; ++j)
            b[j] = *(const f16x8*)(Bb + (j * KB2 + kb) * 512);
#pragma unroll
        for (int i = 0; i < 2; ++i)
#pragma unroll
            for (int j = 0; j < 2; ++j)
                acc[i][j] = __builtin_amdgcn_mfma_f32_16x16x32_f16(a[i], b[j], acc[i][j], 0, 0, 0);
    }

    const int* list = lists + e * T_TOK;
    const int fq = l >> 4, fr = l & 15;
    const int c0 = bx * 128 + w * 32;
#pragma unroll
    for (int i = 0; i < 2; ++i)
#pragma unroll
        for (int r = 0; r < 4; ++r) {
            const int m = m0 + i * 16 + fq * 4 + r;
            if (m < cnt) {
                const int tok = list[m];
                const float pb = probs[tok];
                float* orow = out + (size_t)tok * DIM + c0 + fr;
                orow[0]  = bf16_rne(acc[i][0][r]) * pb;
                orow[16] = bf16_rne(acc[i][1][r]) * pb;
            }
        }
}

// ---------------------------------------------------------------------------
extern "C" void kernel_launch(void* const* d_in, const int* in_sizes, int n_in,
                              void* d_out, int out_size, void* d_ws, size_t ws_size,
                              hipStream_t stream) {
    const float* X  = (const float*)d_in[0];
    const float* rw = (const float*)d_in[1];
    const float* rb = (const float*)d_in[2];
    const float* w1 = (const float*)d_in[3];
    const float* w2 = (const float*)d_in[4];
    const float* w3 = (const float*)d_in[5];
    float* out = (float*)d_out;

    // workspace layout (bytes); total ~116.1 MB
    char* ws = (char*)d_ws;
    int*      counts = (int*)(ws + 0);
    int*      lists  = (int*)(ws + 256);
    float*    probs  = (float*)(ws + 131328);
    const size_t WSZ = 25165824;  // each swizzled weight: 8*NB*KB*512*2 B
    _Float16* w1s = (_Float16*)(ws + 147712);
    _Float16* w2s = (_Float16*)(ws + 147712 + WSZ);
    _Float16* w3s = (_Float16*)(ws + 147712 + 2 * WSZ);
    _Float16* Ag  = (_Float16*)(ws + 147712 + 3 * WSZ);              // 12.6 MB
    _Float16* Hs  = (_Float16*)(ws + 147712 + 3 * WSZ + 12582912);   // 33.6 MB

    hipLaunchKernelGGL(moe_init_kernel, dim3(1), dim3(64), 0, stream, counts);
    hipLaunchKernelGGL(moe_convert_kernel, dim3(16, 64, 24), dim3(256), 0, stream,
                       w1, w2, w3, w1s, w2s, w3s);
    hipLaunchKernelGGL(moe_router_kernel, dim3(T_TOK / 4), dim3(256), 0, stream,
                       X, rw, rb, probs, counts, lists);
    hipLaunchKernelGGL(moe_gather_kernel, dim3(6, 16, 8), dim3(256), 0, stream,
                       X, lists, counts, Ag);
    hipLaunchKernelGGL(moe_gemm1_kernel, dim3(16, 16, 8), dim3(256), 0, stream,
                       Ag, w1s, w2s, counts, Hs);
    hipLaunchKernelGGL(moe_gemm2_kernel, dim3(6, 32, 8), dim3(256), 0, stream,
                       Hs, w3s, lists, counts, probs, out);
}

// Round 3
// 340.496 us; speedup vs baseline: 1.6572x; 1.0256x over previous
//
#include <hip/hip_runtime.h>

// ---------------------------------------------------------------------------
// SwitchMLP (top-1 MoE, SwiGLU) for MI355X / gfx950.  S=1024 B=4 DIM=768
// HID=2048 E=8, f32 in/out.
//
// All GEMM operands pre-staged in f16 MFMA fragment order; GEMM K-loops are
// pure global_load_dwordx4 -> v_mfma, register-double-buffered, no LDS.
//   convert: w1/w2/w3 f32 [K][N] -> swizzled f16 B-operand cells
//   router : f64 logits, argmax, per-expert token lists, max-prob
//   gather : X rows -> Ag (A-operand cells, zero-padded to 64-row tiles)
//   gemm1  : h = silu(A@W1)*(A@W2), epilogue LDS-transpose C->A layout -> Hs
//   gemm2  : out[tok] = bf16_rne(Hs@W3) * prob[tok]
//
// Fragment layouts (HW-validated in rounds 1-2):
//   A-op: lane l holds A[m=l&15][k=(l>>4)*8+j]   (cell = 16m x 32k = 512 f16)
//   B-op: lane l holds B[k=(l>>4)*8+j][n=l&15]   (cell = 32k x 16n = 512 f16)
//   C/D : lane l holds C[row=(l>>4)*4+r][col=l&15]
// ---------------------------------------------------------------------------

#define T_TOK 4096
#define DIM   768
#define HID   2048
#define NE    8
#define ECAP  1024           // per-expert token capacity (~24 sigma margin)

#define KB1 24               // DIM/32  k-cells, gemm1
#define NB1 128              // HID/16  n-cells, w1/w2
#define KB2 64               // HID/32  k-cells, gemm2
#define NB2 48               // DIM/16  n-cells, w3
#define MBC 64               // ECAP/16 m-cells per expert

typedef _Float16 f16x8 __attribute__((ext_vector_type(8)));
typedef float    f32x4 __attribute__((ext_vector_type(4)));

__device__ __forceinline__ float bf16_rne(float v) {
    unsigned u = __float_as_uint(v);
    unsigned r = (u + 0x7fffu + ((u >> 16) & 1u)) & 0xffff0000u;
    return __uint_as_float(r);
}

// ---------------------------------------------------------------------------
__global__ void moe_init_kernel(int* __restrict__ counts) {
    if (threadIdx.x < NE) counts[threadIdx.x] = 0;
}

// ---------------------------------------------------------------------------
// Convert+swizzle one 64k x 128n tile into B-operand cells.
// LDS f32 [k][n] stride 130 (=2 mod 4): float2 writes and b32 column reads
// are both uniform <=2-way on banks. 8 float4 global loads/thread for MLP.
__global__ __launch_bounds__(256) void moe_convert_kernel(
    const float* __restrict__ w1, const float* __restrict__ w2,
    const float* __restrict__ w3, _Float16* __restrict__ w1s,
    _Float16* __restrict__ w2s, _Float16* __restrict__ w3s)
{
    const int bid = blockIdx.x;          // 0..4607
    const float* src; _Float16* dst; int N, KBc, ngrp, kgrp;
    if (bid < 1536) {
        const int e = bid / 192, tile = bid % 192;
        src = w1 + (size_t)e * DIM * HID; dst = w1s + (size_t)e * NB1 * KB1 * 512;
        N = HID; KBc = KB1; ngrp = tile & 15; kgrp = tile >> 4;
    } else if (bid < 3072) {
        const int r = bid - 1536, e = r / 192, tile = r % 192;
        src = w2 + (size_t)e * DIM * HID; dst = w2s + (size_t)e * NB1 * KB1 * 512;
        N = HID; KBc = KB1; ngrp = tile & 15; kgrp = tile >> 4;
    } else {
        const int r = bid - 3072, e = r / 192, tile = r % 192;
        src = w3 + (size_t)e * HID * DIM; dst = w3s + (size_t)e * NB2 * KB2 * 512;
        N = DIM; KBc = KB2; ngrp = tile % 6; kgrp = tile / 6;
    }

    __shared__ float Lt[64 * 130];
    const int t  = threadIdx.x;
    const int c4 = (t & 31) * 4;         // f32 col within 128
    const int r0 = (t >> 5) * 8;         // first of 8 k-rows
    const float* p = src + (size_t)(kgrp * 64 + r0) * N + ngrp * 128 + c4;
    float4 v[8];
#pragma unroll
    for (int j = 0; j < 8; ++j) v[j] = *(const float4*)(p + (size_t)j * N);
#pragma unroll
    for (int j = 0; j < 8; ++j) {
        float* row = &Lt[(r0 + j) * 130 + c4];
        *(float2*)(row)     = make_float2(v[j].x, v[j].y);
        *(float2*)(row + 2) = make_float2(v[j].z, v[j].w);
    }
    __syncthreads();

    const int l = t & 63, w = t >> 6;
    const int fr = l & 15, fq = l >> 4;
#pragma unroll
    for (int i = 0; i < 4; ++i) {
        const int cell = w * 4 + i;      // 16 cells: 2 kbl x 8 nbl
        const int kbl = cell >> 3, nbl = cell & 7;
        f16x8 h;
#pragma unroll
        for (int j = 0; j < 8; ++j)
            h[j] = (_Float16)Lt[(kbl * 32 + fq * 8 + j) * 130 + nbl * 16 + fr];
        const int nb = ngrp * 8 + nbl, kb = kgrp * 2 + kbl;
        *(f16x8*)(dst + ((size_t)nb * KBc + kb) * 512 + l * 8) = h;
    }
}

// ---------------------------------------------------------------------------
// One wave per token: f64 logits (argmax robustness), max softmax prob,
// atomic append to owning expert's list.
__global__ __launch_bounds__(256) void moe_router_kernel(
    const float* __restrict__ X, const float* __restrict__ rw,
    const float* __restrict__ rb, float* __restrict__ probs,
    int* __restrict__ counts, int* __restrict__ lists)
{
    const int t    = blockIdx.x * 4 + (threadIdx.x >> 6);
    const int lane = threadIdx.x & 63;
    const float* x = X + (size_t)t * DIM;

    float xv[12];
#pragma unroll
    for (int j = 0; j < 12; ++j) xv[j] = x[lane + j * 64];

    double lg[NE];
#pragma unroll
    for (int e = 0; e < NE; ++e) {
        double s = 0.0;
#pragma unroll
        for (int j = 0; j < 12; ++j)
            s += (double)xv[j] * (double)rw[(lane + j * 64) * NE + e];
#pragma unroll
        for (int off = 32; off >= 1; off >>= 1) s += __shfl_xor(s, off, 64);
        lg[e] = s + (double)rb[e];
    }

    if (lane == 0) {
        double m = lg[0]; int mi = 0;
#pragma unroll
        for (int e = 1; e < NE; ++e)
            if (lg[e] > m) { m = lg[e]; mi = e; }
        float sum = 0.f;
#pragma unroll
        for (int e = 0; e < NE; ++e) sum += expf((float)(lg[e] - m));
        probs[t] = 1.0f / sum;
        int pos = atomicAdd(&counts[mi], 1);
        lists[mi * T_TOK + pos] = t;
    }
}

// ---------------------------------------------------------------------------
// Gather X rows per expert into A-operand cells (f16), zero-padding rows
// beyond cnt up to the 64-row tile boundary.
__global__ __launch_bounds__(256) void moe_gather_kernel(
    const float* __restrict__ X, const int* __restrict__ lists,
    const int* __restrict__ counts, _Float16* __restrict__ Ag)
{
    const int e = blockIdx.z;
    int cnt = counts[e]; if (cnt > ECAP) cnt = ECAP;
    const int mgrp = blockIdx.y;
    if (mgrp * 64 >= ((cnt + 63) & ~63)) return;
    const int t = threadIdx.x, w = t >> 6, l = t & 63;
    const int mb = mgrp * 4 + w;
    const int m  = mb * 16 + (l & 15);
    const bool valid = (m < cnt);
    const int tok = valid ? lists[e * T_TOK + m] : 0;
    const float* xr = X + (size_t)tok * DIM + (l >> 4) * 8;
#pragma unroll
    for (int i = 0; i < 4; ++i) {
        const int kb = blockIdx.x * 4 + i;
        float4 a = make_float4(0.f, 0.f, 0.f, 0.f), b = a;
        if (valid) {
            a = *(const float4*)(xr + kb * 32);
            b = *(const float4*)(xr + kb * 32 + 4);
        }
        f16x8 h;
        h[0] = (_Float16)a.x; h[1] = (_Float16)a.y; h[2] = (_Float16)a.z; h[3] = (_Float16)a.w;
        h[4] = (_Float16)b.x; h[5] = (_Float16)b.y; h[6] = (_Float16)b.z; h[7] = (_Float16)b.w;
        *(f16x8*)(Ag + ((size_t)(e * MBC + mb) * KB1 + kb) * 512 + l * 8) = h;
    }
}

// ---------------------------------------------------------------------------
// GEMM1: block = 128m x 64n (both W1,W2), wave = 64m x 32n. Register
// double-buffered K-loop (no LDS, no barriers). Epilogue: silu(h1)*h2 -> f16,
// C->A layout via per-wave LDS, write Hs cells.
__global__ __launch_bounds__(256, 3) void moe_gemm1_kernel(
    const _Float16* __restrict__ Ag, const _Float16* __restrict__ w1s,
    const _Float16* __restrict__ w2s, const int* __restrict__ counts,
    _Float16* __restrict__ Hs)
{
    const int e = blockIdx.z;
    int cnt = counts[e]; if (cnt > ECAP) cnt = ECAP;
    const int by = blockIdx.y, bx = blockIdx.x;   // by: 128m, bx: 64n
    if (by * 128 >= cnt) return;
    const int t = threadIdx.x, w = t >> 6, l = t & 63;
    const int wm = w & 1, wn = w >> 1;

    const _Float16* Ab  = Ag + ((size_t)((e * MBC + by * 8 + wm * 4) * KB1)) * 512 + l * 8;
    const int nb0 = e * NB1 + bx * 4 + wn * 2;
    const _Float16* B1b = w1s + ((size_t)nb0 * KB1) * 512 + l * 8;
    const _Float16* B2b = w2s + ((size_t)nb0 * KB1) * 512 + l * 8;

    f32x4 acc1[4][2], acc2[4][2];
    const f32x4 zero = {0.f, 0.f, 0.f, 0.f};
#pragma unroll
    for (int i = 0; i < 4; ++i)
#pragma unroll
        for (int j = 0; j < 2; ++j) { acc1[i][j] = zero; acc2[i][j] = zero; }

    f16x8 a0[4], p0[2], q0[2], a1[4], p1[2], q1[2];

    auto LD = [&](f16x8* a, f16x8* p, f16x8* q, int kb) {
#pragma unroll
        for (int i = 0; i < 4; ++i)
            a[i] = *(const f16x8*)(Ab + ((size_t)(i * KB1 + kb)) * 512);
#pragma unroll
        for (int j = 0; j < 2; ++j) {
            p[j] = *(const f16x8*)(B1b + ((size_t)(j * KB1 + kb)) * 512);
            q[j] = *(const f16x8*)(B2b + ((size_t)(j * KB1 + kb)) * 512);
        }
    };
    auto FM = [&](const f16x8* a, const f16x8* p, const f16x8* q) {
#pragma unroll
        for (int i = 0; i < 4; ++i)
#pragma unroll
            for (int j = 0; j < 2; ++j) {
                acc1[i][j] = __builtin_amdgcn_mfma_f32_16x16x32_f16(a[i], p[j], acc1[i][j], 0, 0, 0);
                acc2[i][j] = __builtin_amdgcn_mfma_f32_16x16x32_f16(a[i], q[j], acc2[i][j], 0, 0, 0);
            }
    };

    LD(a0, p0, q0, 0);
    int kb = 0;
    for (; kb + 2 < KB1; kb += 2) {
        LD(a1, p1, q1, kb + 1);
        FM(a0, p0, q0);
        LD(a0, p0, q0, kb + 2);
        FM(a1, p1, q1);
    }
    LD(a1, p1, q1, kb + 1);
    FM(a0, p0, q0);
    FM(a1, p1, q1);

    // epilogue: silu(h1)*h2 -> f16; C-layout -> A-layout via per-wave LDS
    __shared__ _Float16 Ep[4][64 * 40];
    const int fq = l >> 4, fr = l & 15;
#pragma unroll
    for (int i = 0; i < 4; ++i)
#pragma unroll
        for (int j = 0; j < 2; ++j)
#pragma unroll
            for (int r = 0; r < 4; ++r) {
                const float h1 = acc1[i][j][r], h2 = acc2[i][j][r];
                const float s  = h1 / (1.f + __expf(-h1)) * h2;
                Ep[w][(i * 16 + fq * 4 + r) * 40 + j * 16 + fr] = (_Float16)s;
            }
    __syncthreads();
    const int kbH = bx * 2 + wn;         // this wave's 32-wide hid cell
#pragma unroll
    for (int i = 0; i < 4; ++i) {
        f16x8 v = *(const f16x8*)&Ep[w][(i * 16 + fr) * 40 + fq * 8];
        *(f16x8*)(Hs + ((size_t)((e * MBC + by * 8 + wm * 4 + i) * KB2 + kbH)) * 512 + l * 8) = v;
    }
}

// ---------------------------------------------------------------------------
// GEMM2: block = 64m x 128n, wave = 64m x 32n, K=2048, register
// double-buffered. Epilogue: bf16_rne(acc) * prob, scatter f32 by token.
__global__ __launch_bounds__(256, 4) void moe_gemm2_kernel(
    const _Float16* __restrict__ Hs, const _Float16* __restrict__ w3s,
    const int* __restrict__ lists, const int* __restrict__ counts,
    const float* __restrict__ probs, float* __restrict__ out)
{
    const int e = blockIdx.z;
    int cnt = counts[e]; if (cnt > ECAP) cnt = ECAP;
    const int by = blockIdx.y, bx = blockIdx.x;   // by: 64m, bx: 128n
    if (by * 64 >= cnt) return;
    const int t = threadIdx.x, w = t >> 6, l = t & 63;

    const _Float16* Ab = Hs + ((size_t)((e * MBC + by * 4) * KB2)) * 512 + l * 8;
    const int nb0 = e * NB2 + bx * 8 + w * 2;
    const _Float16* Bb = w3s + ((size_t)nb0 * KB2) * 512 + l * 8;

    f32x4 acc[4][2];
    const f32x4 zero = {0.f, 0.f, 0.f, 0.f};
#pragma unroll
    for (int i = 0; i < 4; ++i) { acc[i][0] = zero; acc[i][1] = zero; }

    f16x8 a0[4], b0[2], a1[4], b1[2];

    auto LD = [&](f16x8* a, f16x8* b, int kb) {
#pragma unroll
        for (int i = 0; i < 4; ++i)
            a[i] = *(const f16x8*)(Ab + ((size_t)(i * KB2 + kb)) * 512);
#pragma unroll
        for (int j = 0; j < 2; ++j)
            b[j] = *(const f16x8*)(Bb + ((size_t)(j * KB2 + kb)) * 512);
    };
    auto FM = [&](const f16x8* a, const f16x8* b) {
#pragma unroll
        for (int i = 0; i < 4; ++i)
#pragma unroll
            for (int j = 0; j < 2; ++j)
                acc[i][j] = __builtin_amdgcn_mfma_f32_16x16x32_f16(a[i], b[j], acc[i][j], 0, 0, 0);
    };

    LD(a0, b0, 0);
    int kb = 0;
    for (; kb + 2 < KB2; kb += 2) {
        LD(a1, b1, kb + 1);
        FM(a0, b0);
        LD(a0, b0, kb + 2);
        FM(a1, b1);
    }
    LD(a1, b1, kb + 1);
    FM(a0, b0);
    FM(a1, b1);

    const int* list = lists + e * T_TOK;
    const int fq = l >> 4, fr = l & 15;
    const int c0 = bx * 128 + w * 32;
#pragma unroll
    for (int i = 0; i < 4; ++i)
#pragma unroll
        for (int r = 0; r < 4; ++r) {
            const int m = by * 64 + i * 16 + fq * 4 + r;
            if (m < cnt) {
                const int tok = list[m];
                const float pb = probs[tok];
                float* orow = out + (size_t)tok * DIM + c0 + fr;
                orow[0]  = bf16_rne(acc[i][0][r]) * pb;
                orow[16] = bf16_rne(acc[i][1][r]) * pb;
            }
        }
}

// ---------------------------------------------------------------------------
extern "C" void kernel_launch(void* const* d_in, const int* in_sizes, int n_in,
                              void* d_out, int out_size, void* d_ws, size_t ws_size,
                              hipStream_t stream) {
    const float* X  = (const float*)d_in[0];
    const float* rw = (const float*)d_in[1];
    const float* rb = (const float*)d_in[2];
    const float* w1 = (const float*)d_in[3];
    const float* w2 = (const float*)d_in[4];
    const float* w3 = (const float*)d_in[5];
    float* out = (float*)d_out;

    // workspace layout (bytes); total ~121.6 MB
    char* ws = (char*)d_ws;
    int*      counts = (int*)(ws + 0);
    int*      lists  = (int*)(ws + 256);
    float*    probs  = (float*)(ws + 131328);
    const size_t WSZ = 25165824;  // each swizzled weight: 8*NB*KB*512*2 B
    _Float16* w1s = (_Float16*)(ws + 147712);
    _Float16* w2s = (_Float16*)(ws + 147712 + WSZ);
    _Float16* w3s = (_Float16*)(ws + 147712 + 2 * WSZ);
    _Float16* Ag  = (_Float16*)(ws + 147712 + 3 * WSZ);              // 12.6 MB
    _Float16* Hs  = (_Float16*)(ws + 147712 + 3 * WSZ + 12582912);   // 33.6 MB

    hipLaunchKernelGGL(moe_init_kernel, dim3(1), dim3(64), 0, stream, counts);
    hipLaunchKernelGGL(moe_convert_kernel, dim3(4608), dim3(256), 0, stream,
                       w1, w2, w3, w1s, w2s, w3s);
    hipLaunchKernelGGL(moe_router_kernel, dim3(T_TOK / 4), dim3(256), 0, stream,
                       X, rw, rb, probs, counts, lists);
    hipLaunchKernelGGL(moe_gather_kernel, dim3(6, 16, 8), dim3(256), 0, stream,
                       X, lists, counts, Ag);
    hipLaunchKernelGGL(moe_gemm1_kernel, dim3(32, 8, 8), dim3(256), 0, stream,
                       Ag, w1s, w2s, counts, Hs);
    hipLaunchKernelGGL(moe_gemm2_kernel, dim3(6, 16, 8), dim3(256), 0, stream,
                       Hs, w3s, lists, counts, probs, out);
}